// Round 9
// baseline (600.861 us; speedup 1.0000x reference)
//
#include <hip/hip_runtime.h>

#define NN 50000
#define NE 800000
#define SCAN_BLOCKS 196   // 196*256 = 50176 >= NN
#define CPAD 16           // counters padded to 1 per 64B line (atomic contention fix)
#define FILL_BLOCKS 3125

typedef __attribute__((ext_vector_type(8))) short short8;
typedef __attribute__((ext_vector_type(4))) float float4v;

struct __align__(8) us4 { unsigned short x, y, z, w; };
struct __align__(16) us8 { unsigned short v[8]; };

__device__ __forceinline__ unsigned short f2bf(float f) {
    unsigned u = __float_as_uint(f);
    unsigned r = (u + 0x7FFF + ((u >> 16) & 1)) >> 16;   // RNE
    return (unsigned short)r;
}

__device__ __forceinline__ float bf2f(unsigned short u) {
    return __uint_as_float((unsigned)u << 16);
}

__device__ __forceinline__ void gload_lds16(const unsigned short* g, unsigned short* l) {
    __builtin_amdgcn_global_load_lds(
        (const __attribute__((address_space(1))) unsigned int*)g,
        (__attribute__((address_space(3))) unsigned int*)l,
        16, 0, 0);
}

// ---------------- bf16 MFMA GEMM: C[N,M] = A[N,K] @ Bt[M,K]^T ----------------
// 2-phase double-buffered. LDS chunk l = 16x32 subtile, row r's four 16B
// col-chunks stored XOR-permuted: position s holds global chunk s^((r>>1)&3).
//  - staging: lane i -> row i>>2, src chunk (i&3)^((i>>3)&3); each 4-lane
//    group still covers ONE 64B row segment -> coalescing preserved.
//  - fragment read: (col16,q) -> offset col16*32 + (q^((col16>>1)&3))*8;
//    wave-wide bijection onto the 64 16B slots -> 2 lanes/bank = free.
// FILL=1: blocks beyond the GEMM grid run the CSR fill (latency-bound atomic
// scatter) concurrently with the compute-bound GEMM — role-split fusion.
template <int BM, int BN, int WM, int WN, int OUTBF, int FILL>
__global__ __launch_bounds__(256) void gemm_mfma(const unsigned short* __restrict__ A,
                                                 const unsigned short* __restrict__ Bt,
                                                 void* __restrict__ Cv,
                                                 int N, int K, int M, int gx,
                                                 const int* __restrict__ esrc,
                                                 const int* __restrict__ edst,
                                                 const float* __restrict__ ew,
                                                 int* __restrict__ cursor,
                                                 int2* __restrict__ csr) {
    constexpr int BK = 32;
    constexpr int MT = WM / 16;
    constexpr int NT = WN / 16;
    constexpr int WCOLS = BN / WN;

    __shared__ __align__(16) unsigned short As[2][BM * BK];
    __shared__ __align__(16) unsigned short Bs[2][BN * BK];

    int bx, by;
    if constexpr (FILL) {
        const int b = blockIdx.x;
        const int ngemm = gx * (M / BN);
        if (b >= ngemm) {
            int i = (b - ngemm) * 256 + threadIdx.x;
            for (; i < NE; i += FILL_BLOCKS * 256) {
                const int p = atomicAdd(&cursor[(size_t)edst[i] * CPAD], 1);
                csr[p] = make_int2(esrc[i], __float_as_int(ew[i]));
            }
            return;
        }
        bx = b % gx;
        by = b / gx;
    } else {
        bx = blockIdx.x;
        by = blockIdx.y;
    }

    const int tid = threadIdx.x;
    const int lane = tid & 63;
    const int wid = tid >> 6;
    const int col16 = lane & 15;
    const int q = lane >> 4;
    const int wr = (wid / WCOLS) * WM;
    const int wc = (wid % WCOLS) * WN;
    const int rowBase = bx * BM;
    const int colBase = by * BN;

    // staging source: row i>>2, XOR-swizzled col chunk (same 64B line per 4 lanes)
    const int srow = lane >> 2;
    const int scol = ((lane & 3) ^ ((lane >> 3) & 3)) * 8;

    float4v acc[MT][NT];
#pragma unroll
    for (int t = 0; t < MT; ++t)
#pragma unroll
        for (int u = 0; u < NT; ++u)
            acc[t][u] = (float4v)0.f;

    auto stage = [&](int buf, int k0) {
#pragma unroll
        for (int l = wid; l < BM / 16; l += 4) {
            int row = rowBase + 16 * l + srow;
            row = row < N ? row : N - 1;
            gload_lds16(A + (size_t)row * K + k0 + scol, &As[buf][l * 512]);
        }
#pragma unroll
        for (int l = wid; l < BN / 16; l += 4) {
            const int row = colBase + 16 * l + srow;
            gload_lds16(Bt + (size_t)row * K + k0 + scol, &Bs[buf][l * 512]);
        }
    };

    // fragment read offset within a 512-short chunk (XOR matches the store)
    const int frag = col16 * 32 + ((q ^ ((col16 >> 1) & 3))) * 8;
    const int awb = (wr / 16) * 512 + frag;
    const int bwb = (wc / 16) * 512 + frag;

    auto compute = [&](int buf) {
        short8 a[MT], b[NT];
#pragma unroll
        for (int t = 0; t < MT; ++t)
            a[t] = *(const short8*)&As[buf][awb + t * 512];
#pragma unroll
        for (int u = 0; u < NT; ++u)
            b[u] = *(const short8*)&Bs[buf][bwb + u * 512];
#pragma unroll
        for (int t = 0; t < MT; ++t)
#pragma unroll
            for (int u = 0; u < NT; ++u)
                acc[t][u] = __builtin_amdgcn_mfma_f32_16x16x32_bf16(a[t], b[u], acc[t][u], 0, 0, 0);
    };

    stage(0, 0);
    __syncthreads();
    int cur = 0;
    for (int k0 = BK; k0 < K; k0 += BK) {
        stage(cur ^ 1, k0);          // prefetch next tile (issued early)
        compute(cur);                // ds_read+MFMA hide the in-flight loads
        __syncthreads();             // one drain+barrier per K-step
        cur ^= 1;
    }
    compute(cur);

    // epilogue: C/D layout col=lane&15, row=q*4+reg
#pragma unroll
    for (int t = 0; t < MT; ++t) {
        const int row0 = rowBase + wr + t * 16 + q * 4;
#pragma unroll
        for (int u = 0; u < NT; ++u) {
            const int col = colBase + wc + u * 16 + col16;
#pragma unroll
            for (int r = 0; r < 4; ++r) {
                const int row = row0 + r;
                if (row < N) {
                    if (OUTBF)
                        ((unsigned short*)Cv)[(size_t)row * M + col] = f2bf(acc[t][u][r]);
                    else
                        ((float*)Cv)[(size_t)row * M + col] = acc[t][u][r];
                }
            }
        }
    }
}

// ---------------- fused conversion + dst histogram (role-interleaved) ----------------
// Roles interleaved by blockIdx%5 so hist blocks are resident from t=0 and the
// atomic-latency work hides under the BW-bound cvt phase. Counters 1 per 64B line.
#define CH_BLOCKS 16000   // 12800 cvt + 3200 hist
__global__ void cvt_hist(const float* __restrict__ in, unsigned short* __restrict__ out,
                         const int* __restrict__ dst, int* __restrict__ counts) {
    const int b = blockIdx.x;
    if ((b % 5) != 4) {
        const int cb = (b / 5) * 4 + (b % 5);          // dense 0..12799
        const long long n4 = (long long)NN * 512 / 4;
        long long i = (long long)cb * 256 + threadIdx.x;
        const long long stride = 12800LL * 256;
        for (; i < n4; i += stride) {
            const float4 v = *(const float4*)&in[i * 4];
            us4 o = {f2bf(v.x), f2bf(v.y), f2bf(v.z), f2bf(v.w)};
            *(us4*)&out[i * 4] = o;
        }
    } else {
        const int hb = b / 5;                           // dense 0..3199
        int i = hb * 256 + threadIdx.x;
        const int stride = 3200 * 256;
        for (; i < NE; i += stride) atomicAdd(&counts[(size_t)dst[i] * CPAD], 1);
    }
}

// all four W -> Wt transposes in one launch
__global__ void cvt_transpose_all(const float* __restrict__ W1, unsigned short* __restrict__ Wt1,
                                  const float* __restrict__ W2, unsigned short* __restrict__ Wt2,
                                  const float* __restrict__ W3, unsigned short* __restrict__ Wt3,
                                  const float* __restrict__ W4, unsigned short* __restrict__ Wt4) {
    int idx = blockIdx.x * blockDim.x + threadIdx.x;
    const float* W; unsigned short* Wt; int K, M;
    if (idx < 262144)      { W = W1; Wt = Wt1; K = 512; M = 512; }
    else if (idx < 393216) { idx -= 262144; W = W2; Wt = Wt2; K = 512; M = 256; }
    else if (idx < 425984) { idx -= 393216; W = W3; Wt = Wt3; K = 256; M = 128; }
    else if (idx < 434176) { idx -= 425984; W = W4; Wt = Wt4; K = 128; M = 64; }
    else return;
    const int k = idx / M;
    const int m = idx % M;
    Wt[(size_t)m * K + k] = f2bf(W[(size_t)k * M + m]);
}

// ---------------- CSR build ----------------
__global__ void zero_counts_pad(int4* __restrict__ counts4) {
    int i = blockIdx.x * blockDim.x + threadIdx.x;
    if (i < NN * CPAD / 4) counts4[i] = make_int4(0, 0, 0, 0);
}

__global__ __launch_bounds__(256) void scan_partial(const int* __restrict__ counts,
                                                    int* __restrict__ partials) {
    __shared__ int r[256];
    const int t = threadIdx.x;
    const int i = blockIdx.x * 256 + t;
    r[t] = (i < NN) ? counts[(size_t)i * CPAD] : 0;
    __syncthreads();
    for (int s = 128; s > 0; s >>= 1) {
        if (t < s) r[t] += r[t + s];
        __syncthreads();
    }
    if (t == 0) partials[blockIdx.x] = r[0];
}

__global__ __launch_bounds__(256) void scan_base(const int* __restrict__ partials,
                                                 int* __restrict__ bases,
                                                 int* __restrict__ offs) {
    __shared__ int s[256];
    const int t = threadIdx.x;
    const int v = (t < SCAN_BLOCKS) ? partials[t] : 0;
    s[t] = v;
    __syncthreads();
    for (int off = 1; off < 256; off <<= 1) {
        int x = (t >= off) ? s[t - off] : 0;
        __syncthreads();
        s[t] += x;
        __syncthreads();
    }
    if (t < SCAN_BLOCKS) bases[t] = s[t] - v;
    if (t == 255) offs[NN] = s[255];
}

__global__ __launch_bounds__(256) void scan_final(int* __restrict__ counts,
                                                  const int* __restrict__ bases,
                                                  int* __restrict__ offs) {
    __shared__ int s[256];
    const int t = threadIdx.x;
    const int i = blockIdx.x * 256 + t;
    const int v = (i < NN) ? counts[(size_t)i * CPAD] : 0;
    s[t] = v;
    __syncthreads();
    for (int off = 1; off < 256; off <<= 1) {
        int x = (t >= off) ? s[t - off] : 0;
        __syncthreads();
        s[t] += x;
        __syncthreads();
    }
    if (i < NN) {
        const int e = bases[blockIdx.x] + s[t] - v;
        offs[i] = e;
        counts[(size_t)i * CPAD] = e;   // becomes the fill cursor
    }
}

// -------- gather SpMM, XCD column-panel partitioned (bf16 in/out) --------
// blockIdx&7 (round-robin -> XCD) selects a D/8-wide column panel: each XCD
// reads only a 1/8 slice of every h row instead of the full row, cutting the
// 8x cross-XCD L2 duplication of gathered rows (slice: 6.4/3.2/1.6 MB for
// D=512/256/128 vs 4 MB L2). Correctness independent of block->XCD mapping.
template <int D, int RELU>
__global__ __launch_bounds__(256) void spmm_gather_xcd(const int* __restrict__ offs,
                                                       const int2* __restrict__ csr,
                                                       const unsigned short* __restrict__ hp,
                                                       const float* __restrict__ bias,
                                                       unsigned short* __restrict__ outp) {
    constexpr int PW = D / 8;        // panel width (cols)
    constexpr int TPNP = PW / 8;     // threads per node within a panel
    constexpr int NPB = 256 / TPNP;  // nodes per block
    const int tid = threadIdx.x;
    const int p = blockIdx.x & 7;
    const int g = blockIdx.x >> 3;
    const int node = g * NPB + tid / TPNP;
    const int d = p * PW + (tid % TPNP) * 8;
    if (node >= NN) return;
    const int beg = offs[node];
    const int end = offs[node + 1];

    float acc[8] = {};
    int j = beg;
    for (; j + 8 <= end; j += 8) {
        int2 e[8];
#pragma unroll
        for (int t = 0; t < 8; ++t) e[t] = csr[j + t];
        us8 h[8];
#pragma unroll
        for (int t = 0; t < 8; ++t)
            h[t] = *(const us8*)&hp[(long long)e[t].x * D + d];
#pragma unroll
        for (int t = 0; t < 8; ++t) {
            const float w = __int_as_float(e[t].y);
#pragma unroll
            for (int k = 0; k < 8; ++k) acc[k] += w * bf2f(h[t].v[k]);
        }
    }
    for (; j + 2 <= end; j += 2) {
        const int2 e0 = csr[j];
        const int2 e1 = csr[j + 1];
        const us8 h0 = *(const us8*)&hp[(long long)e0.x * D + d];
        const us8 h1 = *(const us8*)&hp[(long long)e1.x * D + d];
        const float w0 = __int_as_float(e0.y);
        const float w1 = __int_as_float(e1.y);
#pragma unroll
        for (int k = 0; k < 8; ++k)
            acc[k] += w0 * bf2f(h0.v[k]) + w1 * bf2f(h1.v[k]);
    }
    if (j < end) {
        const int2 e0 = csr[j];
        const us8 h0 = *(const us8*)&hp[(long long)e0.x * D + d];
        const float w0 = __int_as_float(e0.y);
#pragma unroll
        for (int k = 0; k < 8; ++k) acc[k] += w0 * bf2f(h0.v[k]);
    }
    us8 o;
#pragma unroll
    for (int k = 0; k < 8; ++k) {
        float v = acc[k] + bias[d + k];
        if (RELU) v = fmaxf(v, 0.f);
        o.v[k] = f2bf(v);
    }
    *(us8*)&outp[(long long)node * D + d] = o;
}

// ---------------- gather SpMM (bf16 h input), 8x edge unroll ----------------
// Used for the final layer (f32 output).
template <int D, int RELU, int OUTBF>
__global__ __launch_bounds__(256) void spmm_gather(const int* __restrict__ offs,
                                                   const int2* __restrict__ csr,
                                                   const unsigned short* __restrict__ hp,
                                                   const float* __restrict__ bias,
                                                   void* __restrict__ outv,
                                                   int dbase, int dstride) {
    constexpr int TPN = D / 8;
    constexpr int NPB = 256 / TPN;
    const int tid = threadIdx.x;
    const int node = blockIdx.x * NPB + tid / TPN;
    const int d = dbase + (tid % TPN) * 8;
    if (node >= NN) return;
    const int beg = offs[node];
    const int end = offs[node + 1];

    float acc[8] = {};
    int j = beg;
    for (; j + 8 <= end; j += 8) {
        int2 e[8];
#pragma unroll
        for (int t = 0; t < 8; ++t) e[t] = csr[j + t];
        us8 h[8];
#pragma unroll
        for (int t = 0; t < 8; ++t)
            h[t] = *(const us8*)&hp[(long long)e[t].x * dstride + d];
#pragma unroll
        for (int t = 0; t < 8; ++t) {
            const float w = __int_as_float(e[t].y);
#pragma unroll
            for (int k = 0; k < 8; ++k) acc[k] += w * bf2f(h[t].v[k]);
        }
    }
    for (; j + 2 <= end; j += 2) {
        const int2 e0 = csr[j];
        const int2 e1 = csr[j + 1];
        const us8 h0 = *(const us8*)&hp[(long long)e0.x * dstride + d];
        const us8 h1 = *(const us8*)&hp[(long long)e1.x * dstride + d];
        const float w0 = __int_as_float(e0.y);
        const float w1 = __int_as_float(e1.y);
#pragma unroll
        for (int k = 0; k < 8; ++k)
            acc[k] += w0 * bf2f(h0.v[k]) + w1 * bf2f(h1.v[k]);
    }
    if (j < end) {
        const int2 e0 = csr[j];
        const us8 h0 = *(const us8*)&hp[(long long)e0.x * dstride + d];
        const float w0 = __int_as_float(e0.y);
#pragma unroll
        for (int k = 0; k < 8; ++k) acc[k] += w0 * bf2f(h0.v[k]);
    }
#pragma unroll
    for (int k = 0; k < 8; ++k) {
        acc[k] += bias[d + k];
        if (RELU) acc[k] = fmaxf(acc[k], 0.f);
    }
    if (OUTBF) {
        us8 o;
#pragma unroll
        for (int k = 0; k < 8; ++k) o.v[k] = f2bf(acc[k]);
        *(us8*)((unsigned short*)outv + (long long)node * dstride + d) = o;
    } else {
        float* op = (float*)outv + (long long)node * dstride + d;
        *(float4*)op = make_float4(acc[0], acc[1], acc[2], acc[3]);
        *(float4*)(op + 4) = make_float4(acc[4], acc[5], acc[6], acc[7]);
    }
}

extern "C" void kernel_launch(void* const* d_in, const int* in_sizes, int n_in,
                              void* d_out, int out_size, void* d_ws, size_t ws_size,
                              hipStream_t stream) {
    const float* x    = (const float*)d_in[0];
    const int*   esrc = (const int*)d_in[1];
    const int*   edst = (const int*)d_in[2];
    const float* ew   = (const float*)d_in[3];
    const float* W1 = (const float*)d_in[4];  const float* b1 = (const float*)d_in[5];
    const float* W2 = (const float*)d_in[6];  const float* b2 = (const float*)d_in[7];
    const float* W3 = (const float*)d_in[8];  const float* b3 = (const float*)d_in[9];
    const float* W4 = (const float*)d_in[10]; const float* b4 = (const float*)d_in[11];
    float* out = (float*)d_out;

    // workspace layout (~113 MB)
    char* ws = (char*)d_ws;
    int*   offs    = (int*)ws;                    ws += (NN + 1) * sizeof(int);
    int*   partials= (int*)ws;                    ws += 256 * sizeof(int);
    int*   bases   = (int*)ws;                    ws += 256 * sizeof(int);
    ws = (char*)(((uintptr_t)ws + 63) & ~(uintptr_t)63);
    int*   counts  = (int*)ws;                    ws += (size_t)NN * CPAD * sizeof(int);
    int2*  csr     = (int2*)ws;                   ws += (size_t)NE * sizeof(int2);
    unsigned short* Wt1 = (unsigned short*)ws;    ws += 512 * 512 * sizeof(unsigned short);
    unsigned short* Wt2 = (unsigned short*)ws;    ws += 256 * 512 * sizeof(unsigned short);
    unsigned short* Wt3 = (unsigned short*)ws;    ws += 128 * 256 * sizeof(unsigned short);
    unsigned short* Wt4 = (unsigned short*)ws;    ws += 64 * 128 * sizeof(unsigned short);
    ws = (char*)(((uintptr_t)ws + 255) & ~(uintptr_t)255);
    unsigned short* tmp = (unsigned short*)ws;    ws += (size_t)NN * 512 * sizeof(unsigned short);
    ws = (char*)(((uintptr_t)ws + 255) & ~(uintptr_t)255);
    unsigned short* hb = (unsigned short*)ws;     // N x 512 bf16; x, then h1..h3

    // ---- CSR build + conversions ----
    zero_counts_pad<<<(NN * CPAD / 4 + 255) / 256, 256, 0, stream>>>((int4*)counts);
    cvt_hist<<<CH_BLOCKS, 256, 0, stream>>>(x, hb, edst, counts);
    scan_partial<<<SCAN_BLOCKS, 256, 0, stream>>>(counts, partials);
    scan_base<<<1, 256, 0, stream>>>(partials, bases, offs);
    scan_final<<<SCAN_BLOCKS, 256, 0, stream>>>(counts, bases, offs);
    cvt_transpose_all<<<(434176 + 255) / 256, 256, 0, stream>>>(W1, Wt1, W2, Wt2, W3, Wt3, W4, Wt4);

    const int nby128 = (NN + 127) / 128;   // 391
    const int nby64  = (NN + 63) / 64;     // 782

    // ---- layer 1: K=512, M=512 (GEMM fused with CSR fill: role-split blocks) ----
    gemm_mfma<128, 128, 64, 64, 1, 1><<<nby128 * 4 + FILL_BLOCKS, 256, 0, stream>>>(
        hb, Wt1, tmp, NN, 512, 512, nby128, esrc, edst, ew, counts, csr);
    spmm_gather_xcd<512, 1><<<8 * ((NN + 31) / 32), 256, 0, stream>>>(offs, csr, tmp, b1, hb);
    // ---- layer 2: K=512, M=256 ----
    gemm_mfma<128, 128, 64, 64, 1, 0><<<dim3(nby128, 2), 256, 0, stream>>>(
        hb, Wt2, tmp, NN, 512, 256, 0, nullptr, nullptr, nullptr, nullptr, nullptr);
    spmm_gather_xcd<256, 1><<<8 * ((NN + 63) / 64), 256, 0, stream>>>(offs, csr, tmp, b2, hb);
    // ---- layer 3: K=256, M=128 ----
    gemm_mfma<64, 128, 32, 64, 1, 0><<<dim3(nby64, 1), 256, 0, stream>>>(
        hb, Wt3, tmp, NN, 256, 128, 0, nullptr, nullptr, nullptr, nullptr, nullptr);
    spmm_gather_xcd<128, 1><<<8 * ((NN + 127) / 128), 256, 0, stream>>>(offs, csr, tmp, b3, hb);
    // ---- layer 4: K=128, M=64 ----
    gemm_mfma<64, 64, 32, 32, 1, 0><<<dim3(nby64, 1), 256, 0, stream>>>(
        hb, Wt4, tmp, NN, 128, 64, 0, nullptr, nullptr, nullptr, nullptr, nullptr);
    spmm_gather<64, 0, 0><<<(NN + 31) / 32, 256, 0, stream>>>(offs, csr, tmp, b4, out, 0, 64);
}

// Round 10
// 525.571 us; speedup vs baseline: 1.1433x; 1.1433x over previous
//
#include <hip/hip_runtime.h>

#define NN 50000
#define NE 800000
#define SCAN_BLOCKS 196   // 196*256 = 50176 >= NN
#define CPAD 16           // counters padded to 1 per 64B line (atomic contention fix)
#define FILL_BLOCKS 3125

typedef __attribute__((ext_vector_type(8))) short short8;
typedef __attribute__((ext_vector_type(4))) float float4v;

struct __align__(8) us4 { unsigned short x, y, z, w; };
struct __align__(16) us8 { unsigned short v[8]; };

__device__ __forceinline__ unsigned short f2bf(float f) {
    unsigned u = __float_as_uint(f);
    unsigned r = (u + 0x7FFF + ((u >> 16) & 1)) >> 16;   // RNE
    return (unsigned short)r;
}

__device__ __forceinline__ float bf2f(unsigned short u) {
    return __uint_as_float((unsigned)u << 16);
}

__device__ __forceinline__ void gload_lds16(const unsigned short* g, unsigned short* l) {
    __builtin_amdgcn_global_load_lds(
        (const __attribute__((address_space(1))) unsigned int*)g,
        (__attribute__((address_space(3))) unsigned int*)l,
        16, 0, 0);
}

// ---------------- bf16 MFMA GEMM: C[N,M] = A[N,K] @ Bt[M,K]^T ----------------
// 2-phase double-buffered. LDS chunk l = 16x32 subtile, row r's four 16B
// col-chunks stored XOR-permuted: position s holds global chunk s^((r>>1)&3).
//  - staging: lane i -> row i>>2, src chunk (i&3)^((i>>3)&3); each 4-lane
//    group still covers ONE 64B row segment -> coalescing preserved.
//  - fragment read: (col16,q) -> offset col16*32 + (q^((col16>>1)&3))*8;
//    wave-wide bijection onto the 64 16B slots -> 2 lanes/bank = free.
// FILL=1: blocks beyond the GEMM grid run the CSR fill (latency-bound atomic
// scatter) concurrently with the compute-bound GEMM — role-split fusion.
template <int BM, int BN, int WM, int WN, int OUTBF, int FILL>
__global__ __launch_bounds__(256) void gemm_mfma(const unsigned short* __restrict__ A,
                                                 const unsigned short* __restrict__ Bt,
                                                 void* __restrict__ Cv,
                                                 int N, int K, int M, int gx,
                                                 const int* __restrict__ esrc,
                                                 const int* __restrict__ edst,
                                                 const float* __restrict__ ew,
                                                 int* __restrict__ cursor,
                                                 int2* __restrict__ csr) {
    constexpr int BK = 32;
    constexpr int MT = WM / 16;
    constexpr int NT = WN / 16;
    constexpr int WCOLS = BN / WN;

    __shared__ __align__(16) unsigned short As[2][BM * BK];
    __shared__ __align__(16) unsigned short Bs[2][BN * BK];

    int bx, by;
    if constexpr (FILL) {
        const int b = blockIdx.x;
        const int ngemm = gx * (M / BN);
        if (b >= ngemm) {
            int i = (b - ngemm) * 256 + threadIdx.x;
            for (; i < NE; i += FILL_BLOCKS * 256) {
                const int p = atomicAdd(&cursor[(size_t)edst[i] * CPAD], 1);
                csr[p] = make_int2(esrc[i], __float_as_int(ew[i]));
            }
            return;
        }
        bx = b % gx;
        by = b / gx;
    } else {
        bx = blockIdx.x;
        by = blockIdx.y;
    }

    const int tid = threadIdx.x;
    const int lane = tid & 63;
    const int wid = tid >> 6;
    const int col16 = lane & 15;
    const int q = lane >> 4;
    const int wr = (wid / WCOLS) * WM;
    const int wc = (wid % WCOLS) * WN;
    const int rowBase = bx * BM;
    const int colBase = by * BN;

    // staging source: row i>>2, XOR-swizzled col chunk (same 64B line per 4 lanes)
    const int srow = lane >> 2;
    const int scol = ((lane & 3) ^ ((lane >> 3) & 3)) * 8;

    float4v acc[MT][NT];
#pragma unroll
    for (int t = 0; t < MT; ++t)
#pragma unroll
        for (int u = 0; u < NT; ++u)
            acc[t][u] = (float4v)0.f;

    auto stage = [&](int buf, int k0) {
#pragma unroll
        for (int l = wid; l < BM / 16; l += 4) {
            int row = rowBase + 16 * l + srow;
            row = row < N ? row : N - 1;
            gload_lds16(A + (size_t)row * K + k0 + scol, &As[buf][l * 512]);
        }
#pragma unroll
        for (int l = wid; l < BN / 16; l += 4) {
            const int row = colBase + 16 * l + srow;
            gload_lds16(Bt + (size_t)row * K + k0 + scol, &Bs[buf][l * 512]);
        }
    };

    // fragment read offset within a 512-short chunk (XOR matches the store)
    const int frag = col16 * 32 + ((q ^ ((col16 >> 1) & 3))) * 8;
    const int awb = (wr / 16) * 512 + frag;
    const int bwb = (wc / 16) * 512 + frag;

    auto compute = [&](int buf) {
        short8 a[MT], b[NT];
#pragma unroll
        for (int t = 0; t < MT; ++t)
            a[t] = *(const short8*)&As[buf][awb + t * 512];
#pragma unroll
        for (int u = 0; u < NT; ++u)
            b[u] = *(const short8*)&Bs[buf][bwb + u * 512];
#pragma unroll
        for (int t = 0; t < MT; ++t)
#pragma unroll
            for (int u = 0; u < NT; ++u)
                acc[t][u] = __builtin_amdgcn_mfma_f32_16x16x32_bf16(a[t], b[u], acc[t][u], 0, 0, 0);
    };

    stage(0, 0);
    __syncthreads();
    int cur = 0;
    for (int k0 = BK; k0 < K; k0 += BK) {
        stage(cur ^ 1, k0);          // prefetch next tile (issued early)
        compute(cur);                // ds_read+MFMA hide the in-flight loads
        __syncthreads();             // one drain+barrier per K-step
        cur ^= 1;
    }
    compute(cur);

    // epilogue: C/D layout col=lane&15, row=q*4+reg
#pragma unroll
    for (int t = 0; t < MT; ++t) {
        const int row0 = rowBase + wr + t * 16 + q * 4;
#pragma unroll
        for (int u = 0; u < NT; ++u) {
            const int col = colBase + wc + u * 16 + col16;
#pragma unroll
            for (int r = 0; r < 4; ++r) {
                const int row = row0 + r;
                if (row < N) {
                    if (OUTBF)
                        ((unsigned short*)Cv)[(size_t)row * M + col] = f2bf(acc[t][u][r]);
                    else
                        ((float*)Cv)[(size_t)row * M + col] = acc[t][u][r];
                }
            }
        }
    }
}

// ---------------- fused conversion + dst histogram (role-interleaved) ----------------
// Roles interleaved by blockIdx%5 so hist blocks are resident from t=0 and the
// atomic-latency work hides under the BW-bound cvt phase. Counters 1 per 64B line.
#define CH_BLOCKS 16000   // 12800 cvt + 3200 hist
__global__ void cvt_hist(const float* __restrict__ in, unsigned short* __restrict__ out,
                         const int* __restrict__ dst, int* __restrict__ counts) {
    const int b = blockIdx.x;
    if ((b % 5) != 4) {
        const int cb = (b / 5) * 4 + (b % 5);          // dense 0..12799
        const long long n4 = (long long)NN * 512 / 4;
        long long i = (long long)cb * 256 + threadIdx.x;
        const long long stride = 12800LL * 256;
        for (; i < n4; i += stride) {
            const float4 v = *(const float4*)&in[i * 4];
            us4 o = {f2bf(v.x), f2bf(v.y), f2bf(v.z), f2bf(v.w)};
            *(us4*)&out[i * 4] = o;
        }
    } else {
        const int hb = b / 5;                           // dense 0..3199
        int i = hb * 256 + threadIdx.x;
        const int stride = 3200 * 256;
        for (; i < NE; i += stride) atomicAdd(&counts[(size_t)dst[i] * CPAD], 1);
    }
}

// all four W -> Wt transposes in one launch
__global__ void cvt_transpose_all(const float* __restrict__ W1, unsigned short* __restrict__ Wt1,
                                  const float* __restrict__ W2, unsigned short* __restrict__ Wt2,
                                  const float* __restrict__ W3, unsigned short* __restrict__ Wt3,
                                  const float* __restrict__ W4, unsigned short* __restrict__ Wt4) {
    int idx = blockIdx.x * blockDim.x + threadIdx.x;
    const float* W; unsigned short* Wt; int K, M;
    if (idx < 262144)      { W = W1; Wt = Wt1; K = 512; M = 512; }
    else if (idx < 393216) { idx -= 262144; W = W2; Wt = Wt2; K = 512; M = 256; }
    else if (idx < 425984) { idx -= 393216; W = W3; Wt = Wt3; K = 256; M = 128; }
    else if (idx < 434176) { idx -= 425984; W = W4; Wt = Wt4; K = 128; M = 64; }
    else return;
    const int k = idx / M;
    const int m = idx % M;
    Wt[(size_t)m * K + k] = f2bf(W[(size_t)k * M + m]);
}

// ---------------- CSR build ----------------
__global__ void zero_counts_pad(int4* __restrict__ counts4) {
    int i = blockIdx.x * blockDim.x + threadIdx.x;
    if (i < NN * CPAD / 4) counts4[i] = make_int4(0, 0, 0, 0);
}

__global__ __launch_bounds__(256) void scan_partial(const int* __restrict__ counts,
                                                    int* __restrict__ partials) {
    __shared__ int r[256];
    const int t = threadIdx.x;
    const int i = blockIdx.x * 256 + t;
    r[t] = (i < NN) ? counts[(size_t)i * CPAD] : 0;
    __syncthreads();
    for (int s = 128; s > 0; s >>= 1) {
        if (t < s) r[t] += r[t + s];
        __syncthreads();
    }
    if (t == 0) partials[blockIdx.x] = r[0];
}

__global__ __launch_bounds__(256) void scan_base(const int* __restrict__ partials,
                                                 int* __restrict__ bases,
                                                 int* __restrict__ offs) {
    __shared__ int s[256];
    const int t = threadIdx.x;
    const int v = (t < SCAN_BLOCKS) ? partials[t] : 0;
    s[t] = v;
    __syncthreads();
    for (int off = 1; off < 256; off <<= 1) {
        int x = (t >= off) ? s[t - off] : 0;
        __syncthreads();
        s[t] += x;
        __syncthreads();
    }
    if (t < SCAN_BLOCKS) bases[t] = s[t] - v;
    if (t == 255) offs[NN] = s[255];
}

__global__ __launch_bounds__(256) void scan_final(int* __restrict__ counts,
                                                  const int* __restrict__ bases,
                                                  int* __restrict__ offs) {
    __shared__ int s[256];
    const int t = threadIdx.x;
    const int i = blockIdx.x * 256 + t;
    const int v = (i < NN) ? counts[(size_t)i * CPAD] : 0;
    s[t] = v;
    __syncthreads();
    for (int off = 1; off < 256; off <<= 1) {
        int x = (t >= off) ? s[t - off] : 0;
        __syncthreads();
        s[t] += x;
        __syncthreads();
    }
    if (i < NN) {
        const int e = bases[blockIdx.x] + s[t] - v;
        offs[i] = e;
        counts[(size_t)i * CPAD] = e;   // becomes the fill cursor
    }
}

// -------- L1 gather: XCD column-panel partitioned (D=512 only) --------
// blockIdx&7 (round-robin -> XCD) selects a 64-col (128B) panel: each XCD
// reads a 1/8 slice of every gathered row (6.4 MB slice vs 51 MB full),
// cutting cross-XCD L2 duplication. 128B/touch keeps full-line coalescing;
// nodes/wave=8 keeps degree-divergence acceptable. Measured: 101 vs 111 µs.
// (D<512 variants regressed -- sub-line touches + degree divergence; reverted.)
template <int D, int RELU>
__global__ __launch_bounds__(256) void spmm_gather_xcd(const int* __restrict__ offs,
                                                       const int2* __restrict__ csr,
                                                       const unsigned short* __restrict__ hp,
                                                       const float* __restrict__ bias,
                                                       unsigned short* __restrict__ outp) {
    constexpr int PW = D / 8;        // panel width (cols)
    constexpr int TPNP = PW / 8;     // threads per node within a panel
    constexpr int NPB = 256 / TPNP;  // nodes per block
    const int tid = threadIdx.x;
    const int p = blockIdx.x & 7;
    const int g = blockIdx.x >> 3;
    const int node = g * NPB + tid / TPNP;
    const int d = p * PW + (tid % TPNP) * 8;
    if (node >= NN) return;
    const int beg = offs[node];
    const int end = offs[node + 1];

    float acc[8] = {};
    int j = beg;
    for (; j + 8 <= end; j += 8) {
        int2 e[8];
#pragma unroll
        for (int t = 0; t < 8; ++t) e[t] = csr[j + t];
        us8 h[8];
#pragma unroll
        for (int t = 0; t < 8; ++t)
            h[t] = *(const us8*)&hp[(long long)e[t].x * D + d];
#pragma unroll
        for (int t = 0; t < 8; ++t) {
            const float w = __int_as_float(e[t].y);
#pragma unroll
            for (int k = 0; k < 8; ++k) acc[k] += w * bf2f(h[t].v[k]);
        }
    }
    for (; j + 2 <= end; j += 2) {
        const int2 e0 = csr[j];
        const int2 e1 = csr[j + 1];
        const us8 h0 = *(const us8*)&hp[(long long)e0.x * D + d];
        const us8 h1 = *(const us8*)&hp[(long long)e1.x * D + d];
        const float w0 = __int_as_float(e0.y);
        const float w1 = __int_as_float(e1.y);
#pragma unroll
        for (int k = 0; k < 8; ++k)
            acc[k] += w0 * bf2f(h0.v[k]) + w1 * bf2f(h1.v[k]);
    }
    if (j < end) {
        const int2 e0 = csr[j];
        const us8 h0 = *(const us8*)&hp[(long long)e0.x * D + d];
        const float w0 = __int_as_float(e0.y);
#pragma unroll
        for (int k = 0; k < 8; ++k) acc[k] += w0 * bf2f(h0.v[k]);
    }
    us8 o;
#pragma unroll
    for (int k = 0; k < 8; ++k) {
        float v = acc[k] + bias[d + k];
        if (RELU) v = fmaxf(v, 0.f);
        o.v[k] = f2bf(v);
    }
    *(us8*)&outp[(long long)node * D + d] = o;
}

// ---------------- gather SpMM (bf16 h input), 8x edge unroll ----------------
// Full-row gather (layers 2-4). Computes columns [dbase, dbase+D).
template <int D, int RELU, int OUTBF>
__global__ __launch_bounds__(256) void spmm_gather(const int* __restrict__ offs,
                                                   const int2* __restrict__ csr,
                                                   const unsigned short* __restrict__ hp,
                                                   const float* __restrict__ bias,
                                                   void* __restrict__ outv,
                                                   int dbase, int dstride) {
    constexpr int TPN = D / 8;
    constexpr int NPB = 256 / TPN;
    const int tid = threadIdx.x;
    const int node = blockIdx.x * NPB + tid / TPN;
    const int d = dbase + (tid % TPN) * 8;
    if (node >= NN) return;
    const int beg = offs[node];
    const int end = offs[node + 1];

    float acc[8] = {};
    int j = beg;
    for (; j + 8 <= end; j += 8) {
        int2 e[8];
#pragma unroll
        for (int t = 0; t < 8; ++t) e[t] = csr[j + t];
        us8 h[8];
#pragma unroll
        for (int t = 0; t < 8; ++t)
            h[t] = *(const us8*)&hp[(long long)e[t].x * dstride + d];
#pragma unroll
        for (int t = 0; t < 8; ++t) {
            const float w = __int_as_float(e[t].y);
#pragma unroll
            for (int k = 0; k < 8; ++k) acc[k] += w * bf2f(h[t].v[k]);
        }
    }
    for (; j + 2 <= end; j += 2) {
        const int2 e0 = csr[j];
        const int2 e1 = csr[j + 1];
        const us8 h0 = *(const us8*)&hp[(long long)e0.x * dstride + d];
        const us8 h1 = *(const us8*)&hp[(long long)e1.x * dstride + d];
        const float w0 = __int_as_float(e0.y);
        const float w1 = __int_as_float(e1.y);
#pragma unroll
        for (int k = 0; k < 8; ++k)
            acc[k] += w0 * bf2f(h0.v[k]) + w1 * bf2f(h1.v[k]);
    }
    if (j < end) {
        const int2 e0 = csr[j];
        const us8 h0 = *(const us8*)&hp[(long long)e0.x * dstride + d];
        const float w0 = __int_as_float(e0.y);
#pragma unroll
        for (int k = 0; k < 8; ++k) acc[k] += w0 * bf2f(h0.v[k]);
    }
#pragma unroll
    for (int k = 0; k < 8; ++k) {
        acc[k] += bias[d + k];
        if (RELU) acc[k] = fmaxf(acc[k], 0.f);
    }
    if (OUTBF) {
        us8 o;
#pragma unroll
        for (int k = 0; k < 8; ++k) o.v[k] = f2bf(acc[k]);
        *(us8*)((unsigned short*)outv + (long long)node * dstride + d) = o;
    } else {
        float* op = (float*)outv + (long long)node * dstride + d;
        *(float4*)op = make_float4(acc[0], acc[1], acc[2], acc[3]);
        *(float4*)(op + 4) = make_float4(acc[4], acc[5], acc[6], acc[7]);
    }
}

extern "C" void kernel_launch(void* const* d_in, const int* in_sizes, int n_in,
                              void* d_out, int out_size, void* d_ws, size_t ws_size,
                              hipStream_t stream) {
    const float* x    = (const float*)d_in[0];
    const int*   esrc = (const int*)d_in[1];
    const int*   edst = (const int*)d_in[2];
    const float* ew   = (const float*)d_in[3];
    const float* W1 = (const float*)d_in[4];  const float* b1 = (const float*)d_in[5];
    const float* W2 = (const float*)d_in[6];  const float* b2 = (const float*)d_in[7];
    const float* W3 = (const float*)d_in[8];  const float* b3 = (const float*)d_in[9];
    const float* W4 = (const float*)d_in[10]; const float* b4 = (const float*)d_in[11];
    float* out = (float*)d_out;

    // workspace layout (~113 MB)
    char* ws = (char*)d_ws;
    int*   offs    = (int*)ws;                    ws += (NN + 1) * sizeof(int);
    int*   partials= (int*)ws;                    ws += 256 * sizeof(int);
    int*   bases   = (int*)ws;                    ws += 256 * sizeof(int);
    ws = (char*)(((uintptr_t)ws + 63) & ~(uintptr_t)63);
    int*   counts  = (int*)ws;                    ws += (size_t)NN * CPAD * sizeof(int);
    int2*  csr     = (int2*)ws;                   ws += (size_t)NE * sizeof(int2);
    unsigned short* Wt1 = (unsigned short*)ws;    ws += 512 * 512 * sizeof(unsigned short);
    unsigned short* Wt2 = (unsigned short*)ws;    ws += 256 * 512 * sizeof(unsigned short);
    unsigned short* Wt3 = (unsigned short*)ws;    ws += 128 * 256 * sizeof(unsigned short);
    unsigned short* Wt4 = (unsigned short*)ws;    ws += 64 * 128 * sizeof(unsigned short);
    ws = (char*)(((uintptr_t)ws + 255) & ~(uintptr_t)255);
    unsigned short* tmp = (unsigned short*)ws;    ws += (size_t)NN * 512 * sizeof(unsigned short);
    ws = (char*)(((uintptr_t)ws + 255) & ~(uintptr_t)255);
    unsigned short* hb = (unsigned short*)ws;     // N x 512 bf16; x, then h1..h3

    // ---- CSR build + conversions ----
    zero_counts_pad<<<(NN * CPAD / 4 + 255) / 256, 256, 0, stream>>>((int4*)counts);
    cvt_hist<<<CH_BLOCKS, 256, 0, stream>>>(x, hb, edst, counts);
    scan_partial<<<SCAN_BLOCKS, 256, 0, stream>>>(counts, partials);
    scan_base<<<1, 256, 0, stream>>>(partials, bases, offs);
    scan_final<<<SCAN_BLOCKS, 256, 0, stream>>>(counts, bases, offs);
    cvt_transpose_all<<<(434176 + 255) / 256, 256, 0, stream>>>(W1, Wt1, W2, Wt2, W3, Wt3, W4, Wt4);

    const int nby128 = (NN + 127) / 128;   // 391
    const int nby64  = (NN + 63) / 64;     // 782

    // ---- layer 1: K=512, M=512 (GEMM fused with CSR fill: role-split blocks) ----
    gemm_mfma<128, 128, 64, 64, 1, 1><<<nby128 * 4 + FILL_BLOCKS, 256, 0, stream>>>(
        hb, Wt1, tmp, NN, 512, 512, nby128, esrc, edst, ew, counts, csr);
    spmm_gather_xcd<512, 1><<<8 * ((NN + 31) / 32), 256, 0, stream>>>(offs, csr, tmp, b1, hb);
    // ---- layer 2: K=512, M=256 ----
    gemm_mfma<128, 128, 64, 64, 1, 0><<<dim3(nby128, 2), 256, 0, stream>>>(
        hb, Wt2, tmp, NN, 512, 256, 0, nullptr, nullptr, nullptr, nullptr, nullptr);
    spmm_gather<256, 1, 1><<<NN / 8, 256, 0, stream>>>(offs, csr, tmp, b2, hb, 0, 256);
    // ---- layer 3: K=256, M=128 ----
    gemm_mfma<64, 128, 32, 64, 1, 0><<<dim3(nby64, 1), 256, 0, stream>>>(
        hb, Wt3, tmp, NN, 256, 128, 0, nullptr, nullptr, nullptr, nullptr, nullptr);
    spmm_gather<128, 1, 1><<<NN / 16, 256, 0, stream>>>(offs, csr, tmp, b3, hb, 0, 128);
    // ---- layer 4: K=128, M=64 ----
    gemm_mfma<64, 64, 32, 32, 1, 0><<<dim3(nby64, 1), 256, 0, stream>>>(
        hb, Wt4, tmp, NN, 128, 64, 0, nullptr, nullptr, nullptr, nullptr, nullptr);
    spmm_gather<64, 0, 0><<<(NN + 31) / 32, 256, 0, stream>>>(offs, csr, tmp, b4, out, 0, 64);
}